// Round 4
// baseline (296.186 us; speedup 1.0000x reference)
//
#include <hip/hip_runtime.h>

// Depthwise separable 4x4 FIR blur (StyleGAN2 upfirdn2d, up=down=1, pad=(2,2)).
// x: [B,C,256,256] f32, kernel: [4,4] f32 separable, out: [B,C,257,257] f32.
//
// out[oh,ow] = sum_i v[i] * H[oh+1-i],  H[r][c] = sum_j w[j]*x[r][c+1-j]
// w[j] = k2d[0][j], v[i] = k2d[i][0]/k2d[0][0] (v0 == 1).
//
// Block = one plane (4 waves = strips of 64/64/64/65 rows). Lane owns 4 output
// columns; ONE float4 load per input row, halo via __shfl. Vertical reuse in a
// 4-deep register ring. KEY CHANGE vs R3: raw-row prefetch is 2 iterations deep
// (BA/BB double buffer) so the consumed row sits ~5 deep in the vmcnt FIFO —
// the compiler can wait with vmcnt(4) and the PREVIOUS ITERATION'S STORE never
// has to drain before compute (vmcnt is a shared load+store FIFO; depth-1
// prefetch forced a store-ack serialization every iteration).
// Stores are nontemporal (write-once data; keep L2/L3 for the input stream).

#define IW 256
#define IH 256
#define OW 257
#define OH 257

typedef float f4u __attribute__((vector_size(16), aligned(4)));

__device__ __forceinline__ float sbc(float v) {   // wave-uniform -> SGPR
    return __uint_as_float(__builtin_amdgcn_readfirstlane(__float_as_uint(v)));
}

__global__ __launch_bounds__(256) void blur_fir_kernel(
    const float* __restrict__ x,
    const float* __restrict__ k2d,
    float* __restrict__ out)
{
    const int tid   = threadIdx.x;
    const int cg    = tid & 63;            // lane = column group: cols [4cg, 4cg+4)
    const int strip = tid >> 6;            // 0..3 (wave = strip)
    const int plane = blockIdx.x;

    const float w0 = sbc(k2d[0]);
    const float w1 = sbc(k2d[1]);
    const float w2 = sbc(k2d[2]);
    const float w3 = sbc(k2d[3]);
    const float inv = 1.0f / w0;
    const float v1 = sbc(k2d[4]  * inv);
    const float v2 = sbc(k2d[8]  * inv);
    const float v3 = sbc(k2d[12] * inv);

    const int   c0 = cg << 2;
    const float mL = (cg > 0)  ? 1.0f : 0.0f;
    const float mR = (cg < 63) ? 1.0f : 0.0f;
    const int   lm = (cg > 0)  ? cg - 1 : 0;   // neighbor-left lane
    const int   lp = (cg < 63) ? cg + 1 : 63;  // neighbor-right lane

    const float* xp = x + ((size_t)plane << 16);
    const int r0    = strip << 6;
    const int nrows = (strip == 3) ? 65 : 64;

    auto loadraw = [&](int r) -> float4 {
        int rr = min(max(r, 0), IH - 1);       // clamp; OOB rows masked in hcomb
        return *(const float4*)(xp + (rr << 8) + c0);
    };
    auto hcomb = [&](float4 Bv, int r, float4& h, float& h4) {
        float rm = (r >= 0 && r < IH) ? 1.0f : 0.0f;
        float lx = __shfl(Bv.z, lm, 64) * mL;  // x[r][c0-2]
        float ly = __shfl(Bv.w, lm, 64) * mL;  // x[r][c0-1]
        float rv = __shfl(Bv.x, lp, 64) * mR;  // x[r][c0+4]
        h.x = w0 * Bv.y + w1 * Bv.x + w2 * ly   + w3 * lx;
        h.y = w0 * Bv.z + w1 * Bv.y + w2 * Bv.x + w3 * ly;
        h.z = w0 * Bv.w + w1 * Bv.z + w2 * Bv.y + w3 * Bv.x;
        h.w = w0 * rv   + w1 * Bv.w + w2 * Bv.z + w3 * Bv.y;
        h4  = w2 * Bv.w + w3 * Bv.z;           // out col 256 (lane 63 only)
        h.x *= rm; h.y *= rm; h.z *= rm; h.w *= rm; h4 *= rm;
    };

    // Prime ring H(r0-2)..H(r0+1); raw rows r0+2 (BA) and r0+3 (BB) in flight.
    float4 hm2, hm1, h0, hp1;
    float  sm2, sm1, s0, sp1;
    { float4 B = loadraw(r0 - 2); hcomb(B, r0 - 2, hm2, sm2); }
    { float4 B = loadraw(r0 - 1); hcomb(B, r0 - 1, hm1, sm1); }
    { float4 B = loadraw(r0    ); hcomb(B, r0    , h0,  s0 ); }
    { float4 B = loadraw(r0 + 1); hcomb(B, r0 + 1, hp1, sp1); }
    float4 BA = loadraw(r0 + 2);               // consumed at i=0
    float4 BB = loadraw(r0 + 3);               // consumed at i=1

    float* op = out + (size_t)plane * (OW * OH) + (size_t)r0 * OW + c0;
    const bool last = (cg == 63);

    #pragma unroll 2
    for (int i = 0; i < nrows; ++i) {
        float4 BN = loadraw(r0 + i + 4);       // for iteration i+2 (depth-2)

        float4 hn; float sn;
        hcomb(BA, r0 + i + 2, hn, sn);         // row loaded 2 iters ago -> vmcnt(4)

        float4 res;
        res.x = hp1.x + v1 * h0.x + v2 * hm1.x + v3 * hm2.x;
        res.y = hp1.y + v1 * h0.y + v2 * hm1.y + v3 * hm2.y;
        res.z = hp1.z + v1 * h0.z + v2 * hm1.z + v3 * hm2.z;
        res.w = hp1.w + v1 * h0.w + v2 * hm1.w + v3 * hm2.w;
        f4u rv = {res.x, res.y, res.z, res.w};
        __builtin_nontemporal_store(rv, (f4u*)op);
        if (last) {
            float e = sp1 + v1 * s0 + v2 * sm1 + v3 * sm2;
            __builtin_nontemporal_store(e, op + 4);
        }
        op += OW;

        hm2 = hm1; hm1 = h0; h0 = hp1; hp1 = hn;
        sm2 = sm1; sm1 = s0; s0 = sp1; sp1 = sn;
        BA = BB; BB = BN;                      // static rotation (unroll 2)
    }
}

extern "C" void kernel_launch(void* const* d_in, const int* in_sizes, int n_in,
                              void* d_out, int out_size, void* d_ws, size_t ws_size,
                              hipStream_t stream) {
    const float* x   = (const float*)d_in[0];
    const float* k2d = (const float*)d_in[1];
    float* out = (float*)d_out;

    int nplanes = in_sizes[0] >> 16;           // B*C = 2048
    blur_fir_kernel<<<nplanes, 256, 0, stream>>>(x, k2d, out);
}

// Round 5
// 247.394 us; speedup vs baseline: 1.1972x; 1.1972x over previous
//
#include <hip/hip_runtime.h>

// Depthwise separable 4x4 FIR blur (StyleGAN2 upfirdn2d, up=down=1, pad=(2,2)).
// x: [B,C,256,256] f32, kernel: [4,4] f32 separable, out: [B,C,257,257] f32.
//
// out[q] = H[q+1] + v1*H[q] + v2*H[q-1] + v3*H[q-2],  H[r][c] = sum_j w[j]*x[r][c+1-j]
// w[j] = k2d[0][j], v[i] = k2d[i][0]/k2d[0][0] (v0 == 1).
//
// R5 change: 4 OUTPUT ROWS PER ITERATION per wave. Each iteration loads input
// rows rb+1..rb+4 as one contiguous 4KB burst (prefetched one iteration ahead),
// so each wave's DRAM visits are 4KB-sequential instead of 1KB — amortizing
// DRAM row activations 4x (R2-R4 all plateaued at ~262us with 8192 scattered
// 1KB-burst streams at only 3.3 TB/s; neither VALU, occupancy, nor MLP was
// the binding resource). Halo via __shfl; H-ring carries 3 rows across groups.
// Regular stores (NT stores regressed in R4).

#define IW 256
#define IH 256
#define OW 257
#define OH 257

typedef float f4u __attribute__((vector_size(16), aligned(4)));

__device__ __forceinline__ float sbc(float v) {   // wave-uniform -> SGPR
    return __uint_as_float(__builtin_amdgcn_readfirstlane(__float_as_uint(v)));
}

__global__ __launch_bounds__(256) void blur_fir_kernel(
    const float* __restrict__ x,
    const float* __restrict__ k2d,
    float* __restrict__ out)
{
    const int tid   = threadIdx.x;
    const int cg    = tid & 63;            // lane = column group: cols [4cg, 4cg+4)
    const int strip = tid >> 6;            // 0..3 (wave = 64-row strip)
    const int plane = blockIdx.x;

    const float w0 = sbc(k2d[0]);
    const float w1 = sbc(k2d[1]);
    const float w2 = sbc(k2d[2]);
    const float w3 = sbc(k2d[3]);
    const float inv = 1.0f / w0;
    const float v1 = sbc(k2d[4]  * inv);
    const float v2 = sbc(k2d[8]  * inv);
    const float v3 = sbc(k2d[12] * inv);

    const int   c0 = cg << 2;
    const float mL = (cg > 0)  ? 1.0f : 0.0f;
    const float mR = (cg < 63) ? 1.0f : 0.0f;
    const int   lm = (cg > 0)  ? cg - 1 : 0;   // neighbor-left lane
    const int   lp = (cg < 63) ? cg + 1 : 63;  // neighbor-right lane

    const float* xp = x + ((size_t)plane << 16);
    const int r0 = strip << 6;

    auto loadraw = [&](int r) -> float4 {
        int rr = min(max(r, 0), IH - 1);       // clamp; OOB rows masked in hcomb
        return *(const float4*)(xp + (rr << 8) + c0);
    };
    auto hcomb = [&](float4 Bv, int r, float4& h, float& h4) {
        float rm = (r >= 0 && r < IH) ? 1.0f : 0.0f;
        float lx = __shfl(Bv.z, lm, 64) * mL;  // x[r][c0-2]
        float ly = __shfl(Bv.w, lm, 64) * mL;  // x[r][c0-1]
        float rv = __shfl(Bv.x, lp, 64) * mR;  // x[r][c0+4]
        h.x = w0 * Bv.y + w1 * Bv.x + w2 * ly   + w3 * lx;
        h.y = w0 * Bv.z + w1 * Bv.y + w2 * Bv.x + w3 * ly;
        h.z = w0 * Bv.w + w1 * Bv.z + w2 * Bv.y + w3 * Bv.x;
        h.w = w0 * rv   + w1 * Bv.w + w2 * Bv.z + w3 * Bv.y;
        h4  = w2 * Bv.w + w3 * Bv.z;           // out col 256 (lane 63 only)
        h.x *= rm; h.y *= rm; h.z *= rm; h.w *= rm; h4 *= rm;
    };
    auto vcomb = [&](float4 a, float4 b, float4 c, float4 d) -> float4 {
        float4 r;
        r.x = a.x + v1 * b.x + v2 * c.x + v3 * d.x;
        r.y = a.y + v1 * b.y + v2 * c.y + v3 * d.y;
        r.z = a.z + v1 * b.z + v2 * c.z + v3 * d.z;
        r.w = a.w + v1 * b.w + v2 * c.w + v3 * d.w;
        return r;
    };

    // Carry ring: C0=H[rb-2], C1=H[rb-1], C2=H[rb]  (+ col-256 scalars)
    float4 C0, C1, C2; float sc0, sc1, sc2;
    { float4 B = loadraw(r0 - 2); hcomb(B, r0 - 2, C0, sc0); }
    { float4 B = loadraw(r0 - 1); hcomb(B, r0 - 1, C1, sc1); }
    { float4 B = loadraw(r0    ); hcomb(B, r0    , C2, sc2); }

    // Current raw group: input rows rb+1..rb+4 (4KB contiguous per wave)
    float4 G0 = loadraw(r0 + 1);
    float4 G1 = loadraw(r0 + 2);
    float4 G2 = loadraw(r0 + 3);
    float4 G3 = loadraw(r0 + 4);

    float* op = out + (size_t)plane * (OW * OH) + (size_t)r0 * OW + c0;
    const bool last = (cg == 63);

    #pragma unroll 2
    for (int g = 0; g < 16; ++g) {
        const int rb = r0 + (g << 2);
        // prefetch next group's rows (4KB contiguous burst), consumed next iter
        float4 N0 = loadraw(rb + 5);
        float4 N1 = loadraw(rb + 6);
        float4 N2 = loadraw(rb + 7);
        float4 N3 = loadraw(rb + 8);

        float4 F0, F1, F2, F3; float sf0, sf1, sf2, sf3;
        hcomb(G0, rb + 1, F0, sf0);
        hcomb(G1, rb + 2, F1, sf1);
        hcomb(G2, rb + 3, F2, sf2);
        hcomb(G3, rb + 4, F3, sf3);

        float4 R0 = vcomb(F0, C2, C1, C0);     // out row rb
        float4 R1 = vcomb(F1, F0, C2, C1);     // out row rb+1
        float4 R2 = vcomb(F2, F1, F0, C2);     // out row rb+2
        float4 R3 = vcomb(F3, F2, F1, F0);     // out row rb+3
        *(f4u*)(op         ) = (f4u){R0.x, R0.y, R0.z, R0.w};
        *(f4u*)(op +     OW) = (f4u){R1.x, R1.y, R1.z, R1.w};
        *(f4u*)(op + 2 * OW) = (f4u){R2.x, R2.y, R2.z, R2.w};
        *(f4u*)(op + 3 * OW) = (f4u){R3.x, R3.y, R3.z, R3.w};
        if (last) {
            op[4]          = sf0 + v1 * sc2 + v2 * sc1 + v3 * sc0;
            op[OW + 4]     = sf1 + v1 * sf0 + v2 * sc2 + v3 * sc1;
            op[2 * OW + 4] = sf2 + v1 * sf1 + v2 * sf0 + v3 * sc2;
            op[3 * OW + 4] = sf3 + v1 * sf2 + v2 * sf1 + v3 * sf0;
        }
        op += 4 * OW;

        C0 = F1;  C1 = F2;  C2 = F3;
        sc0 = sf1; sc1 = sf2; sc2 = sf3;
        G0 = N0; G1 = N1; G2 = N2; G3 = N3;
    }

    if (strip == 3) {                           // output row 256 (H[257] == 0)
        float4 R;
        R.x = v1 * C2.x + v2 * C1.x + v3 * C0.x;
        R.y = v1 * C2.y + v2 * C1.y + v3 * C0.y;
        R.z = v1 * C2.z + v2 * C1.z + v3 * C0.z;
        R.w = v1 * C2.w + v2 * C1.w + v3 * C0.w;
        *(f4u*)op = (f4u){R.x, R.y, R.z, R.w};
        if (last) op[4] = v1 * sc2 + v2 * sc1 + v3 * sc0;
    }
}

extern "C" void kernel_launch(void* const* d_in, const int* in_sizes, int n_in,
                              void* d_out, int out_size, void* d_ws, size_t ws_size,
                              hipStream_t stream) {
    const float* x   = (const float*)d_in[0];
    const float* k2d = (const float*)d_in[1];
    float* out = (float*)d_out;

    int nplanes = in_sizes[0] >> 16;           // B*C = 2048
    blur_fir_kernel<<<nplanes, 256, 0, stream>>>(x, k2d, out);
}